// Round 3
// baseline (1127.962 us; speedup 1.0000x reference)
//
#include <hip/hip_runtime.h>
#include <hip/hip_bf16.h>
#include <math.h>

#define B_ 2
#define A_ 9
#define N_ 1024
#define P_ 4
#define D_ 256
#define H_ 8
#define DH_ 32
#define ROWS_ (B_*N_)   // 2048
#define KS_ 8           // K-split factor for chain
#define KSL_ (N_/KS_)   // 128 contraction elems per block
#define MSP_ 552        // Ms plane stride (floats): 552%32==8 -> planes staggered across banks
#define ADJ_ELEMS_ ((size_t)B_*A_*N_*N_)

// ---------------- prep: softmax(relu(kernels)) over A axis + 1/diag(degree) ----------------
__global__ void prep_kernel(const float* __restrict__ kernels, const float* __restrict__ degree,
                            float* __restrict__ soft, float* __restrict__ invd)
{
    int t = threadIdx.x;
    if (blockIdx.x == 0) {
        if (t < H_*P_) {
            int h = t >> 2, p = t & 3;
            float vals[A_];
            float m = 0.0f;
            #pragma unroll
            for (int a = 0; a < A_; a++) {
                float v = kernels[h*A_*P_ + a*P_ + p];
                v = v > 0.0f ? v : 0.0f;
                vals[a] = v;
                m = fmaxf(m, v);
            }
            float s = 0.0f;
            #pragma unroll
            for (int a = 0; a < A_; a++) { vals[a] = expf(vals[a] - m); s += vals[a]; }
            float inv = 1.0f / s;
            #pragma unroll
            for (int a = 0; a < A_; a++) soft[h*A_*P_ + a*P_ + p] = vals[a] * inv;
        }
    } else {
        int idx = (blockIdx.x - 1) * 256 + t;
        if (idx < ROWS_) {
            int b = idx >> 10, n = idx & (N_-1);
            invd[idx] = 1.0f / degree[(size_t)b*N_*N_ + (size_t)n*N_ + n];
        }
    }
}

// ---------------- adjacency fp32 -> bf16 (RNE), float4 -> ushort4 ----------------
__global__ void adj2bf_kernel(const float* __restrict__ in, ushort* __restrict__ out, int n4)
{
    int i = blockIdx.x * 256 + threadIdx.x;
    int stride = gridDim.x * 256;
    for (; i < n4; i += stride) {
        float4 v = ((const float4*)in)[i];
        ushort4 o;
        uint u;
        u = __float_as_uint(v.x); u += 0x7fffu + ((u>>16)&1u); o.x = (ushort)(u>>16);
        u = __float_as_uint(v.y); u += 0x7fffu + ((u>>16)&1u); o.y = (ushort)(u>>16);
        u = __float_as_uint(v.z); u += 0x7fffu + ((u>>16)&1u); o.z = (ushort)(u>>16);
        u = __float_as_uint(v.w); u += 0x7fffu + ((u>>16)&1u); o.w = (ushort)(u>>16);
        ((ushort4*)out)[i] = o;
    }
}

// ---------------- chain (K-split, fused heads): Pp[ks] = M_step[:,ks-slice] @ Tin[ks-slice,:] ----
// grid = B * 128 rowblks * KS_ = 2048 blocks; 256 threads; 8 blocks/CU.
// Block: 8 output rows x 256 cols (ALL 8 heads -> adjacency read once), m-slice 128, chunk 64.
template<bool BF>
__global__ __launch_bounds__(256, 8)
void chain_kernel(const float* __restrict__ adj, const ushort* __restrict__ adjb,
                  const float* __restrict__ soft,
                  const float* __restrict__ Tin, float* __restrict__ Pp, int step)
{
    __shared__ __align__(16) float Ms[8*MSP_];
    __shared__ float soft_s[8][9];

    int bid    = blockIdx.x;
    int ks     = bid & (KS_-1);
    int rowblk = (bid >> 3) & 127;
    int b      = bid >> 10;
    int n0     = rowblk * 8;
    int tid    = threadIdx.x;

    if (tid < 72) {
        int h = tid / 9, a = tid % 9;
        soft_s[h][a] = soft[h*A_*P_ + a*P_ + step];
    }
    __syncthreads();

    // mixing mapping: row = tid>>5 (0..7), kk = (tid&31)*2
    int mrow = tid >> 5;
    int mkk  = (tid & 31) * 2;

    // compute mapping: 256 = rsub(4) x hh(8) x e(8); 2 rows, 4 cols (float4) per thread
    int e    = tid & 7;
    int hh   = (tid >> 3) & 7;
    int rsub = tid >> 6;
    int col  = hh*32 + e*4;
    int r0   = rsub*2;

    float acc0x=0.f, acc0y=0.f, acc0z=0.f, acc0w=0.f;
    float acc1x=0.f, acc1y=0.f, acc1z=0.f, acc1w=0.f;

    const float* Tin_b = Tin + (size_t)b*N_*D_;

    #pragma unroll
    for (int chunk = 0; chunk < KSL_/64; chunk++) {
        int m0 = ks*KSL_ + chunk*64;

        // ---- load adjacency (2 k per thread, 9 relations) ----
        float lo[9], hi[9];
        if constexpr (BF) {
            #pragma unroll
            for (int a = 0; a < A_; a++) {
                uint v = *(const uint*)&adjb[(((size_t)b*A_ + a)*N_ + (n0+mrow))*N_ + m0 + mkk];
                lo[a] = __uint_as_float(v << 16);
                hi[a] = __uint_as_float(v & 0xffff0000u);
            }
        } else {
            #pragma unroll
            for (int a = 0; a < A_; a++) {
                float2 v = *(const float2*)&adj[(((size_t)b*A_ + a)*N_ + (n0+mrow))*N_ + m0 + mkk];
                lo[a] = v.x; hi[a] = v.y;
            }
        }
        if (chunk > 0) __syncthreads();   // ensure previous compute done before overwriting Ms
        // ---- mix all 8 heads ----
        #pragma unroll
        for (int h = 0; h < 8; h++) {
            float sl = soft_s[h][0]*lo[0], sh = soft_s[h][0]*hi[0];
            #pragma unroll
            for (int a = 1; a < A_; a++) { sl += soft_s[h][a]*lo[a]; sh += soft_s[h][a]*hi[a]; }
            *(float2*)&Ms[h*MSP_ + mrow*68 + mkk] = make_float2(sl, sh);
        }
        __syncthreads();

        // ---- accumulate: acc[r][c] += M[r][k] * T[k][col+c] over 64 k ----
        #pragma unroll
        for (int k4 = 0; k4 < 16; k4++) {
            int kr = m0 + k4*4;
            float4 t0 = *(const float4*)&Tin_b[(size_t)(kr+0)*D_ + col];
            float4 t1 = *(const float4*)&Tin_b[(size_t)(kr+1)*D_ + col];
            float4 t2 = *(const float4*)&Tin_b[(size_t)(kr+2)*D_ + col];
            float4 t3 = *(const float4*)&Tin_b[(size_t)(kr+3)*D_ + col];
            float4 ma = *(const float4*)&Ms[hh*MSP_ + (r0+0)*68 + k4*4];
            float4 mb = *(const float4*)&Ms[hh*MSP_ + (r0+1)*68 + k4*4];
            acc0x += ma.x*t0.x + ma.y*t1.x + ma.z*t2.x + ma.w*t3.x;
            acc0y += ma.x*t0.y + ma.y*t1.y + ma.z*t2.y + ma.w*t3.y;
            acc0z += ma.x*t0.z + ma.y*t1.z + ma.z*t2.z + ma.w*t3.z;
            acc0w += ma.x*t0.w + ma.y*t1.w + ma.z*t2.w + ma.w*t3.w;
            acc1x += mb.x*t0.x + mb.y*t1.x + mb.z*t2.x + mb.w*t3.x;
            acc1y += mb.x*t0.y + mb.y*t1.y + mb.z*t2.y + mb.w*t3.y;
            acc1z += mb.x*t0.z + mb.y*t1.z + mb.z*t2.z + mb.w*t3.z;
            acc1w += mb.x*t0.w + mb.y*t1.w + mb.z*t2.w + mb.w*t3.w;
        }
    }

    size_t outbase = ((size_t)ks*ROWS_ + (size_t)b*N_)*D_;
    *(float4*)&Pp[outbase + (size_t)(n0+r0+0)*D_ + col] = make_float4(acc0x, acc0y, acc0z, acc0w);
    *(float4*)&Pp[outbase + (size_t)(n0+r0+1)*D_ + col] = make_float4(acc1x, acc1y, acc1z, acc1w);
}

// ---------------- reduce the KS_ partial slabs; apply inv-degree scale on step 0 -------------
__global__ void chain_reduce(const float* __restrict__ Pp, float* __restrict__ Tout,
                             const float* __restrict__ invd, int step)
{
    int idx = blockIdx.x * 256 + threadIdx.x;      // one float4 per thread
    int row = idx / (D_/4);
    int c4  = (idx % (D_/4)) * 4;
    float4 s = make_float4(0.f, 0.f, 0.f, 0.f);
    #pragma unroll
    for (int ks = 0; ks < KS_; ks++) {
        float4 v = *(const float4*)&Pp[((size_t)ks*ROWS_ + row)*D_ + c4];
        s.x += v.x; s.y += v.y; s.z += v.z; s.w += v.w;
    }
    float scale = (step == 0) ? invd[row] : 1.0f;
    s.x *= scale; s.y *= scale; s.z *= scale; s.w *= scale;
    *(float4*)&Tout[(size_t)row*D_ + c4] = s;
}

// ---------------- generic 64x64-tile SIMT GEMM, 4x4 microtile ----------------
// MODE 0: C = A @ Wv(cat) + Bv     MODE 1: C = A @ B + add
// MODE 2: C = gelu_exact(A @ B + bias)   MODE 3: C = A @ B + bias + add
#define BK 16
template<int MODE>
__global__ void gemm_kernel(const float* __restrict__ A, const float* __restrict__ Bm,
                            const float* __restrict__ bias, const float* __restrict__ add,
                            float* __restrict__ C, int M, int Ncols, int K)
{
    __shared__ __align__(16) float As[BK][68];
    __shared__ __align__(16) float Bs[BK][68];
    int m0 = blockIdx.x * 64;
    int n0 = blockIdx.y * 64;
    int tid = threadIdx.x;
    int tx = tid & 15, ty = tid >> 4;

    float acc[4][4];
    #pragma unroll
    for (int i = 0; i < 4; i++)
        #pragma unroll
        for (int j = 0; j < 4; j++) acc[i][j] = 0.0f;

    for (int k0 = 0; k0 < K; k0 += BK) {
        {
            int m = tid >> 2;
            int k = (tid & 3) * 4;
            float4 v = *(const float4*)&A[(size_t)(m0+m)*K + k0 + k];
            As[k+0][m] = v.x; As[k+1][m] = v.y; As[k+2][m] = v.z; As[k+3][m] = v.w;
        }
        {
            int k = tid >> 4;
            int n = (tid & 15) * 4;
            float4 v;
            if constexpr (MODE == 0) {
                int c = n0 + n; int h = c >> 5; int ee = c & 31;
                v = *(const float4*)&Bm[(size_t)h*D_*DH_ + (size_t)(k0+k)*DH_ + ee];
            } else {
                v = *(const float4*)&Bm[(size_t)(k0+k)*Ncols + n0 + n];
            }
            *(float4*)&Bs[k][n] = v;
        }
        __syncthreads();
        #pragma unroll
        for (int k = 0; k < BK; k++) {
            float4 a4 = *(const float4*)&As[k][ty*4];
            float4 b4 = *(const float4*)&Bs[k][tx*4];
            acc[0][0] += a4.x*b4.x; acc[0][1] += a4.x*b4.y; acc[0][2] += a4.x*b4.z; acc[0][3] += a4.x*b4.w;
            acc[1][0] += a4.y*b4.x; acc[1][1] += a4.y*b4.y; acc[1][2] += a4.y*b4.z; acc[1][3] += a4.y*b4.w;
            acc[2][0] += a4.z*b4.x; acc[2][1] += a4.z*b4.y; acc[2][2] += a4.z*b4.z; acc[2][3] += a4.z*b4.w;
            acc[3][0] += a4.w*b4.x; acc[3][1] += a4.w*b4.y; acc[3][2] += a4.w*b4.z; acc[3][3] += a4.w*b4.w;
        }
        __syncthreads();
    }

    #pragma unroll
    for (int i = 0; i < 4; i++) {
        int row  = m0 + ty*4 + i;
        int nloc = n0 + tx*4;
        float o[4];
        #pragma unroll
        for (int j = 0; j < 4; j++) {
            float v = acc[i][j];
            int c = nloc + j;
            if constexpr (MODE == 0) {
                int h = c >> 5, ee = c & 31, n = row & (N_-1);
                v += bias[(size_t)h*N_*DH_ + (size_t)n*DH_ + ee];
            }
            if constexpr (MODE == 1) {
                v += add[(size_t)row*Ncols + c];
            }
            if constexpr (MODE == 2) {
                v += bias[c];
                v = 0.5f * v * (1.0f + erff(v * 0.70710678118654752f));
            }
            if constexpr (MODE == 3) {
                v += bias[c] + add[(size_t)row*Ncols + c];
            }
            o[j] = v;
        }
        float4 ov = make_float4(o[0], o[1], o[2], o[3]);
        *(float4*)&C[(size_t)row*Ncols + nloc] = ov;
    }
}

// ---------------- layernorm over last dim W (256 or 512), one row per block ----------------
__global__ void ln_kernel(const float* __restrict__ in, float* __restrict__ out,
                          const float* __restrict__ g, const float* __restrict__ bta, int W)
{
    __shared__ float row[512];
    __shared__ float red[256];
    int r = blockIdx.x;
    int tid = threadIdx.x;
    const float* ip = in + (size_t)r * W;

    float local = 0.0f;
    for (int i = tid; i < W; i += 256) { float v = ip[i]; row[i] = v; local += v; }
    red[tid] = local;
    __syncthreads();
    for (int s = 128; s > 0; s >>= 1) {
        if (tid < s) red[tid] += red[tid + s];
        __syncthreads();
    }
    float mean = red[0] / (float)W;
    __syncthreads();

    float lv = 0.0f;
    for (int i = tid; i < W; i += 256) { float d = row[i] - mean; lv += d*d; }
    red[tid] = lv;
    __syncthreads();
    for (int s = 128; s > 0; s >>= 1) {
        if (tid < s) red[tid] += red[tid + s];
        __syncthreads();
    }
    float var = red[0] / (float)W;
    float rstd = 1.0f / sqrtf(var + 1e-12f);

    float* op = out + (size_t)r * W;
    for (int i = tid; i < W; i += 256) op[i] = (row[i] - mean) * rstd * g[i] + bta[i];
}

extern "C" void kernel_launch(void* const* d_in, const int* in_sizes, int n_in,
                              void* d_out, int out_size, void* d_ws, size_t ws_size,
                              hipStream_t stream)
{
    const float* adj    = (const float*)d_in[0];
    const float* degree = (const float*)d_in[1];
    const float* x      = (const float*)d_in[2];
    const float* kern   = (const float*)d_in[3];
    const float* Wv     = (const float*)d_in[4];
    const float* Bv     = (const float*)d_in[5];
    const float* W0     = (const float*)d_in[6];
    const float* gamma2 = (const float*)d_in[7];
    const float* beta2  = (const float*)d_in[8];
    const float* W1     = (const float*)d_in[9];
    const float* b1     = (const float*)d_in[10];
    const float* gf     = (const float*)d_in[11];
    const float* bf_    = (const float*)d_in[12];
    const float* W2     = (const float*)d_in[13];
    const float* b2f    = (const float*)d_in[14];
    float* out = (float*)d_out;
    float* ws  = (float*)d_ws;

    // ws layout (float units)
    size_t off = 0;
    float* soft  = ws + off; off += 512;
    float* invd  = ws + off; off += 2048;
    float* T0    = ws + off; off += (size_t)ROWS_*D_;
    float* T1    = ws + off; off += (size_t)ROWS_*D_;
    float* resid = ws + off; off += (size_t)ROWS_*D_;
    float* hbuf  = ws + off; off += (size_t)ROWS_*D_;
    float* fbuf  = ws + off; off += (size_t)ROWS_*2*D_;
    float* fbuf2 = ws + off; off += (size_t)ROWS_*2*D_;
    float* Pp    = ws + off; off += (size_t)KS_*ROWS_*D_;
    ushort* adjb = (ushort*)(ws + off);
    size_t needed_bytes = (off + ADJ_ELEMS_/2) * sizeof(float);
    bool use_bf = (ws_size >= needed_bytes);

    // 1) soft weights + inverse degree diag
    prep_kernel<<<9, 256, 0, stream>>>(kern, degree, soft, invd);
    // 1b) adjacency -> bf16 (if workspace allows)
    if (use_bf) {
        int n4 = (int)(ADJ_ELEMS_/4);
        adj2bf_kernel<<<2048, 256, 0, stream>>>(adj, adjb, n4);
    }
    // 2) V = x @ Wv (+Bv), concat layout [B*N][256] col = h*32+e
    gemm_kernel<0><<<dim3(ROWS_/64, D_/64), 256, 0, stream>>>(x, Wv, Bv, nullptr, T0, ROWS_, D_, D_);
    // 3) chain right-to-left with K-split partials + reduce; inv-degree scale on step 0
    int chain_grid  = B_*128*KS_;                    // 2048
    int reduce_grid = (ROWS_*D_/4) / 256;            // 512
    if (use_bf) {
        chain_kernel<true><<<chain_grid, 256, 0, stream>>>(adj, adjb, soft, T0, Pp, 3);
        chain_reduce<<<reduce_grid, 256, 0, stream>>>(Pp, T1, invd, 3);
        chain_kernel<true><<<chain_grid, 256, 0, stream>>>(adj, adjb, soft, T1, Pp, 2);
        chain_reduce<<<reduce_grid, 256, 0, stream>>>(Pp, T0, invd, 2);
        chain_kernel<true><<<chain_grid, 256, 0, stream>>>(adj, adjb, soft, T0, Pp, 1);
        chain_reduce<<<reduce_grid, 256, 0, stream>>>(Pp, T1, invd, 1);
        chain_kernel<true><<<chain_grid, 256, 0, stream>>>(adj, adjb, soft, T1, Pp, 0);
        chain_reduce<<<reduce_grid, 256, 0, stream>>>(Pp, T0, invd, 0);
    } else {
        chain_kernel<false><<<chain_grid, 256, 0, stream>>>(adj, adjb, soft, T0, Pp, 3);
        chain_reduce<<<reduce_grid, 256, 0, stream>>>(Pp, T1, invd, 3);
        chain_kernel<false><<<chain_grid, 256, 0, stream>>>(adj, adjb, soft, T1, Pp, 2);
        chain_reduce<<<reduce_grid, 256, 0, stream>>>(Pp, T0, invd, 2);
        chain_kernel<false><<<chain_grid, 256, 0, stream>>>(adj, adjb, soft, T0, Pp, 1);
        chain_reduce<<<reduce_grid, 256, 0, stream>>>(Pp, T1, invd, 1);
        chain_kernel<false><<<chain_grid, 256, 0, stream>>>(adj, adjb, soft, T1, Pp, 0);
        chain_reduce<<<reduce_grid, 256, 0, stream>>>(Pp, T0, invd, 0);
    }
    // 4) residual = attn @ W0 + x
    gemm_kernel<1><<<dim3(ROWS_/64, D_/64), 256, 0, stream>>>(T0, W0, nullptr, x, resid, ROWS_, D_, D_);
    // 5) h = LN(residual)
    ln_kernel<<<ROWS_, 256, 0, stream>>>(resid, hbuf, gamma2, beta2, D_);
    // 6) f = gelu(h @ W1 + b1)
    gemm_kernel<2><<<dim3(ROWS_/64, (2*D_)/64), 256, 0, stream>>>(hbuf, W1, b1, nullptr, fbuf, ROWS_, 2*D_, D_);
    // 7) f = LN(f)
    ln_kernel<<<ROWS_, 256, 0, stream>>>(fbuf, fbuf2, gf, bf_, 2*D_);
    // 8) out = f @ W2 + b2f + residual
    gemm_kernel<3><<<dim3(ROWS_/64, D_/64), 256, 0, stream>>>(fbuf2, W2, b2f, resid, out, ROWS_, D_, 2*D_);
}

// Round 4
// 287.463 us; speedup vs baseline: 3.9238x; 3.9238x over previous
//
#include <hip/hip_runtime.h>
#include <hip/hip_bf16.h>
#include <math.h>

#define B_ 2
#define A_ 9
#define N_ 1024
#define P_ 4
#define D_ 256
#define H_ 8
#define DH_ 32
#define ROWS_ (B_*N_)   // 2048
#define KS_ 8           // K-split factor for chain
#define KSL_ (N_/KS_)   // 128 contraction elems per block
#define MH_ 1100        // ushort stride per head plane in LDS (2200B -> 550 words, 550%32=6)
#define MR_ 136         // ushort stride per row within a head plane
#define ADJ_ELEMS_ ((size_t)B_*A_*N_*N_)

__device__ __forceinline__ uint pack2_bf(float x, float y) {
    uint ux = __float_as_uint(x); ux += 0x7fffu + ((ux >> 16) & 1u);
    uint uy = __float_as_uint(y); uy += 0x7fffu + ((uy >> 16) & 1u);
    return (ux >> 16) | (uy & 0xffff0000u);
}

// ---------------- prep: softmax(relu(kernels)) over A axis + 1/diag(degree) ----------------
__global__ void prep_kernel(const float* __restrict__ kernels, const float* __restrict__ degree,
                            float* __restrict__ soft, float* __restrict__ invd)
{
    int t = threadIdx.x;
    if (blockIdx.x == 0) {
        if (t < H_*P_) {
            int h = t >> 2, p = t & 3;
            float vals[A_];
            float m = 0.0f;
            #pragma unroll
            for (int a = 0; a < A_; a++) {
                float v = kernels[h*A_*P_ + a*P_ + p];
                v = v > 0.0f ? v : 0.0f;
                vals[a] = v;
                m = fmaxf(m, v);
            }
            float s = 0.0f;
            #pragma unroll
            for (int a = 0; a < A_; a++) { vals[a] = expf(vals[a] - m); s += vals[a]; }
            float inv = 1.0f / s;
            #pragma unroll
            for (int a = 0; a < A_; a++) soft[h*A_*P_ + a*P_ + p] = vals[a] * inv;
        }
    } else {
        int idx = (blockIdx.x - 1) * 256 + t;
        if (idx < ROWS_) {
            int b = idx >> 10, n = idx & (N_-1);
            invd[idx] = 1.0f / degree[(size_t)b*N_*N_ + (size_t)n*N_ + n];
        }
    }
}

// ---------------- pack adjacency fp32 -> bf16 in block-consumption order ----------------
// dst layout: [b][rowblk(128)][ks(8)][a(9)][r(8)][kk(128)] bf16; one uint4 (8 bf16) per thread.
__global__ void adj_pack_kernel(const float* __restrict__ in, ushort* __restrict__ out)
{
    int j = blockIdx.x * 256 + threadIdx.x;   // uint4 index; grid covers ADJ_ELEMS_/8 exactly
    int kk8 = j & 15;
    int r   = (j >> 4) & 7;
    int t   = j >> 7;          // 0..18431 = (b*128+rowblk)*8*9 ... decoded below
    int a   = t % 9;
    int q   = t / 9;           // b*1024 + rowblk*8 + ks
    int ks  = q & 7;
    int rowblk = (q >> 3) & 127;
    int b   = q >> 10;
    int n = rowblk*8 + r;
    int m = ks*128 + kk8*8;
    const float* src = &in[(((size_t)b*A_ + a)*N_ + n)*N_ + m];
    float4 v0 = *(const float4*)src;
    float4 v1 = *(const float4*)(src + 4);
    uint4 o;
    o.x = pack2_bf(v0.x, v0.y);
    o.y = pack2_bf(v0.z, v0.w);
    o.z = pack2_bf(v1.x, v1.y);
    o.w = pack2_bf(v1.z, v1.w);
    ((uint4*)out)[j] = o;
}

// ---------------- chain (K-split, packed adjacency): Pp[ks] = M_step[:,slice] @ Tin[slice,:] ----
// grid = B*128*KS_ = 2048 blocks; 256 threads; 8 blocks/CU; block = 8 rows x 256 cols, k-depth 128.
__global__ __launch_bounds__(256, 8)
void chain_kernel(const ushort* __restrict__ adjp, const float* __restrict__ soft,
                  const float* __restrict__ Tin, float* __restrict__ Pp, int step)
{
    __shared__ ushort Msb[8*MH_];     // 8 head planes of mixed M, bf16, bank-staggered
    __shared__ float soft_s[8][9];

    int bid    = blockIdx.x;
    int ks     = bid & (KS_-1);
    int rowblk = (bid >> 3) & 127;
    int b      = bid >> 10;
    int n0     = rowblk * 8;
    int tid    = threadIdx.x;

    if (tid < 72) {
        int h = tid / 9, a = tid % 9;
        soft_s[h][a] = soft[h*A_*P_ + a*P_ + step];
    }
    __syncthreads();

    // ---- mixing phase: each thread owns (r = tid>>5, 4 consecutive kk); reads 9 relations ----
    {
        int r   = tid >> 5;
        int kkg = (tid & 31) * 4;
        const ushort* sl = adjp + (size_t)(((b*128 + rowblk)*8 + ks)*9) * (8*128);
        float va[9][4];
        #pragma unroll
        for (int a = 0; a < A_; a++) {
            uint2 u = *(const uint2*)&sl[(a*8 + r)*128 + kkg];
            va[a][0] = __uint_as_float(u.x << 16);
            va[a][1] = __uint_as_float(u.x & 0xffff0000u);
            va[a][2] = __uint_as_float(u.y << 16);
            va[a][3] = __uint_as_float(u.y & 0xffff0000u);
        }
        #pragma unroll
        for (int h = 0; h < H_; h++) {
            float m0 = soft_s[h][0]*va[0][0];
            float m1 = soft_s[h][0]*va[0][1];
            float m2 = soft_s[h][0]*va[0][2];
            float m3 = soft_s[h][0]*va[0][3];
            #pragma unroll
            for (int a = 1; a < A_; a++) {
                m0 += soft_s[h][a]*va[a][0];
                m1 += soft_s[h][a]*va[a][1];
                m2 += soft_s[h][a]*va[a][2];
                m3 += soft_s[h][a]*va[a][3];
            }
            uint2 w;
            w.x = pack2_bf(m0, m1);
            w.y = pack2_bf(m2, m3);
            *(uint2*)&Msb[h*MH_ + r*MR_ + kkg] = w;
        }
    }
    __syncthreads();

    // ---- compute phase: 256 = rsub(4) x hh(8) x e(8); 2 rows x 4 cols per thread ----
    int e    = tid & 7;
    int hh   = (tid >> 3) & 7;
    int rsub = tid >> 6;
    int col  = hh*32 + e*4;
    int r0   = rsub*2;
    int mbase = ks*KSL_;

    float acc0x=0.f, acc0y=0.f, acc0z=0.f, acc0w=0.f;
    float acc1x=0.f, acc1y=0.f, acc1z=0.f, acc1w=0.f;

    const float* Tin_b = Tin + (size_t)b*N_*D_;

    #pragma unroll 4
    for (int k4 = 0; k4 < 32; k4++) {
        int kr = mbase + k4*4;
        float4 t0 = *(const float4*)&Tin_b[(size_t)(kr+0)*D_ + col];
        float4 t1 = *(const float4*)&Tin_b[(size_t)(kr+1)*D_ + col];
        float4 t2 = *(const float4*)&Tin_b[(size_t)(kr+2)*D_ + col];
        float4 t3 = *(const float4*)&Tin_b[(size_t)(kr+3)*D_ + col];
        uint2 ma = *(const uint2*)&Msb[hh*MH_ + (r0+0)*MR_ + k4*4];
        uint2 mb = *(const uint2*)&Msb[hh*MH_ + (r0+1)*MR_ + k4*4];
        float ma0 = __uint_as_float(ma.x << 16);
        float ma1 = __uint_as_float(ma.x & 0xffff0000u);
        float ma2 = __uint_as_float(ma.y << 16);
        float ma3 = __uint_as_float(ma.y & 0xffff0000u);
        float mb0 = __uint_as_float(mb.x << 16);
        float mb1 = __uint_as_float(mb.x & 0xffff0000u);
        float mb2 = __uint_as_float(mb.y << 16);
        float mb3 = __uint_as_float(mb.y & 0xffff0000u);
        acc0x += ma0*t0.x + ma1*t1.x + ma2*t2.x + ma3*t3.x;
        acc0y += ma0*t0.y + ma1*t1.y + ma2*t2.y + ma3*t3.y;
        acc0z += ma0*t0.z + ma1*t1.z + ma2*t2.z + ma3*t3.z;
        acc0w += ma0*t0.w + ma1*t1.w + ma2*t2.w + ma3*t3.w;
        acc1x += mb0*t0.x + mb1*t1.x + mb2*t2.x + mb3*t3.x;
        acc1y += mb0*t0.y + mb1*t1.y + mb2*t2.y + mb3*t3.y;
        acc1z += mb0*t0.z + mb1*t1.z + mb2*t2.z + mb3*t3.z;
        acc1w += mb0*t0.w + mb1*t1.w + mb2*t2.w + mb3*t3.w;
    }

    size_t outbase = ((size_t)ks*ROWS_ + (size_t)b*N_)*D_;
    *(float4*)&Pp[outbase + (size_t)(n0+r0+0)*D_ + col] = make_float4(acc0x, acc0y, acc0z, acc0w);
    *(float4*)&Pp[outbase + (size_t)(n0+r0+1)*D_ + col] = make_float4(acc1x, acc1y, acc1z, acc1w);
}

// ---------------- reduce the KS_ partial slabs; apply inv-degree scale on step 0 -------------
__global__ void chain_reduce(const float* __restrict__ Pp, float* __restrict__ Tout,
                             const float* __restrict__ invd, int step)
{
    int idx = blockIdx.x * 256 + threadIdx.x;      // one float4 per thread
    int row = idx / (D_/4);
    int c4  = (idx % (D_/4)) * 4;
    float4 s = make_float4(0.f, 0.f, 0.f, 0.f);
    #pragma unroll
    for (int ks = 0; ks < KS_; ks++) {
        float4 v = *(const float4*)&Pp[((size_t)ks*ROWS_ + row)*D_ + c4];
        s.x += v.x; s.y += v.y; s.z += v.z; s.w += v.w;
    }
    float scale = (step == 0) ? invd[row] : 1.0f;
    s.x *= scale; s.y *= scale; s.z *= scale; s.w *= scale;
    *(float4*)&Tout[(size_t)row*D_ + c4] = s;
}

// ---------------- generic 64x64-tile SIMT GEMM, 4x4 microtile ----------------
// MODE 0: C = A @ Wv(cat) + Bv     MODE 1: C = A @ B + add
// MODE 2: C = gelu_exact(A @ B + bias)   MODE 3: C = A @ B + bias + add
#define BK 16
template<int MODE>
__global__ void gemm_kernel(const float* __restrict__ A, const float* __restrict__ Bm,
                            const float* __restrict__ bias, const float* __restrict__ add,
                            float* __restrict__ C, int M, int Ncols, int K)
{
    __shared__ __align__(16) float As[BK][68];
    __shared__ __align__(16) float Bs[BK][68];
    int m0 = blockIdx.x * 64;
    int n0 = blockIdx.y * 64;
    int tid = threadIdx.x;
    int tx = tid & 15, ty = tid >> 4;

    float acc[4][4];
    #pragma unroll
    for (int i = 0; i < 4; i++)
        #pragma unroll
        for (int j = 0; j < 4; j++) acc[i][j] = 0.0f;

    for (int k0 = 0; k0 < K; k0 += BK) {
        {
            int m = tid >> 2;
            int k = (tid & 3) * 4;
            float4 v = *(const float4*)&A[(size_t)(m0+m)*K + k0 + k];
            As[k+0][m] = v.x; As[k+1][m] = v.y; As[k+2][m] = v.z; As[k+3][m] = v.w;
        }
        {
            int k = tid >> 4;
            int n = (tid & 15) * 4;
            float4 v;
            if constexpr (MODE == 0) {
                int c = n0 + n; int h = c >> 5; int ee = c & 31;
                v = *(const float4*)&Bm[(size_t)h*D_*DH_ + (size_t)(k0+k)*DH_ + ee];
            } else {
                v = *(const float4*)&Bm[(size_t)(k0+k)*Ncols + n0 + n];
            }
            *(float4*)&Bs[k][n] = v;
        }
        __syncthreads();
        #pragma unroll
        for (int k = 0; k < BK; k++) {
            float4 a4 = *(const float4*)&As[k][ty*4];
            float4 b4 = *(const float4*)&Bs[k][tx*4];
            acc[0][0] += a4.x*b4.x; acc[0][1] += a4.x*b4.y; acc[0][2] += a4.x*b4.z; acc[0][3] += a4.x*b4.w;
            acc[1][0] += a4.y*b4.x; acc[1][1] += a4.y*b4.y; acc[1][2] += a4.y*b4.z; acc[1][3] += a4.y*b4.w;
            acc[2][0] += a4.z*b4.x; acc[2][1] += a4.z*b4.y; acc[2][2] += a4.z*b4.z; acc[2][3] += a4.z*b4.w;
            acc[3][0] += a4.w*b4.x; acc[3][1] += a4.w*b4.y; acc[3][2] += a4.w*b4.z; acc[3][3] += a4.w*b4.w;
        }
        __syncthreads();
    }

    #pragma unroll
    for (int i = 0; i < 4; i++) {
        int row  = m0 + ty*4 + i;
        int nloc = n0 + tx*4;
        float o[4];
        #pragma unroll
        for (int j = 0; j < 4; j++) {
            float v = acc[i][j];
            int c = nloc + j;
            if constexpr (MODE == 0) {
                int h = c >> 5, ee = c & 31, n = row & (N_-1);
                v += bias[(size_t)h*N_*DH_ + (size_t)n*DH_ + ee];
            }
            if constexpr (MODE == 1) {
                v += add[(size_t)row*Ncols + c];
            }
            if constexpr (MODE == 2) {
                v += bias[c];
                v = 0.5f * v * (1.0f + erff(v * 0.70710678118654752f));
            }
            if constexpr (MODE == 3) {
                v += bias[c] + add[(size_t)row*Ncols + c];
            }
            o[j] = v;
        }
        float4 ov = make_float4(o[0], o[1], o[2], o[3]);
        *(float4*)&C[(size_t)row*Ncols + nloc] = ov;
    }
}

// ---------------- layernorm over last dim W (256 or 512), one row per block ----------------
__global__ void ln_kernel(const float* __restrict__ in, float* __restrict__ out,
                          const float* __restrict__ g, const float* __restrict__ bta, int W)
{
    __shared__ float row[512];
    __shared__ float red[256];
    int r = blockIdx.x;
    int tid = threadIdx.x;
    const float* ip = in + (size_t)r * W;

    float local = 0.0f;
    for (int i = tid; i < W; i += 256) { float v = ip[i]; row[i] = v; local += v; }
    red[tid] = local;
    __syncthreads();
    for (int s = 128; s > 0; s >>= 1) {
        if (tid < s) red[tid] += red[tid + s];
        __syncthreads();
    }
    float mean = red[0] / (float)W;
    __syncthreads();

    float lv = 0.0f;
    for (int i = tid; i < W; i += 256) { float d = row[i] - mean; lv += d*d; }
    red[tid] = lv;
    __syncthreads();
    for (int s = 128; s > 0; s >>= 1) {
        if (tid < s) red[tid] += red[tid + s];
        __syncthreads();
    }
    float var = red[0] / (float)W;
    float rstd = 1.0f / sqrtf(var + 1e-12f);

    float* op = out + (size_t)r * W;
    for (int i = tid; i < W; i += 256) op[i] = (row[i] - mean) * rstd * g[i] + bta[i];
}

extern "C" void kernel_launch(void* const* d_in, const int* in_sizes, int n_in,
                              void* d_out, int out_size, void* d_ws, size_t ws_size,
                              hipStream_t stream)
{
    const float* adj    = (const float*)d_in[0];
    const float* degree = (const float*)d_in[1];
    const float* x      = (const float*)d_in[2];
    const float* kern   = (const float*)d_in[3];
    const float* Wv     = (const float*)d_in[4];
    const float* Bv     = (const float*)d_in[5];
    const float* W0     = (const float*)d_in[6];
    const float* gamma2 = (const float*)d_in[7];
    const float* beta2  = (const float*)d_in[8];
    const float* W1     = (const float*)d_in[9];
    const float* b1     = (const float*)d_in[10];
    const float* gf     = (const float*)d_in[11];
    const float* bf_    = (const float*)d_in[12];
    const float* W2     = (const float*)d_in[13];
    const float* b2f    = (const float*)d_in[14];
    float* out = (float*)d_out;
    float* ws  = (float*)d_ws;

    // ws layout (float units)
    size_t off = 0;
    float* soft  = ws + off; off += 512;
    float* invd  = ws + off; off += 2048;
    float* T0    = ws + off; off += (size_t)ROWS_*D_;
    float* T1    = ws + off; off += (size_t)ROWS_*D_;
    float* resid = ws + off; off += (size_t)ROWS_*D_;
    float* hbuf  = ws + off; off += (size_t)ROWS_*D_;
    float* fbuf  = ws + off; off += (size_t)ROWS_*2*D_;
    float* fbuf2 = ws + off; off += (size_t)ROWS_*2*D_;
    float* Pp    = ws + off; off += (size_t)KS_*ROWS_*D_;
    ushort* adjp = (ushort*)(ws + off);   // ADJ_ELEMS_ bf16 = 37.75 MB

    // 1) soft weights + inverse degree diag
    prep_kernel<<<9, 256, 0, stream>>>(kern, degree, soft, invd);
    // 1b) pack adjacency into bf16 block-consumption order
    adj_pack_kernel<<<(int)(ADJ_ELEMS_/8/256), 256, 0, stream>>>(adj, adjp);
    // 2) V = x @ Wv (+Bv), concat layout [B*N][256] col = h*32+e
    gemm_kernel<0><<<dim3(ROWS_/64, D_/64), 256, 0, stream>>>(x, Wv, Bv, nullptr, T0, ROWS_, D_, D_);
    // 3) chain right-to-left with K-split partials + reduce; inv-degree scale on step 0
    int chain_grid  = B_*128*KS_;                    // 2048
    int reduce_grid = (ROWS_*D_/4) / 256;            // 512
    chain_kernel<<<chain_grid, 256, 0, stream>>>(adjp, soft, T0, Pp, 3);
    chain_reduce<<<reduce_grid, 256, 0, stream>>>(Pp, T1, invd, 3);
    chain_kernel<<<chain_grid, 256, 0, stream>>>(adjp, soft, T1, Pp, 2);
    chain_reduce<<<reduce_grid, 256, 0, stream>>>(Pp, T0, invd, 2);
    chain_kernel<<<chain_grid, 256, 0, stream>>>(adjp, soft, T0, Pp, 1);
    chain_reduce<<<reduce_grid, 256, 0, stream>>>(Pp, T1, invd, 1);
    chain_kernel<<<chain_grid, 256, 0, stream>>>(adjp, soft, T1, Pp, 0);
    chain_reduce<<<reduce_grid, 256, 0, stream>>>(Pp, T0, invd, 0);
    // 4) residual = attn @ W0 + x
    gemm_kernel<1><<<dim3(ROWS_/64, D_/64), 256, 0, stream>>>(T0, W0, nullptr, x, resid, ROWS_, D_, D_);
    // 5) h = LN(residual)
    ln_kernel<<<ROWS_, 256, 0, stream>>>(resid, hbuf, gamma2, beta2, D_);
    // 6) f = gelu(h @ W1 + b1)
    gemm_kernel<2><<<dim3(ROWS_/64, (2*D_)/64), 256, 0, stream>>>(hbuf, W1, b1, nullptr, fbuf, ROWS_, 2*D_, D_);
    // 7) f = LN(f)
    ln_kernel<<<ROWS_, 256, 0, stream>>>(fbuf, fbuf2, gf, bf_, 2*D_);
    // 8) out = f @ W2 + b2f + residual
    gemm_kernel<3><<<dim3(ROWS_/64, D_/64), 256, 0, stream>>>(fbuf2, W2, b2f, resid, out, ROWS_, D_, 2*D_);
}